// Round 18
// baseline (102.398 us; speedup 1.0000x reference)
//
#include <hip/hip_runtime.h>
#include <hip/hip_bf16.h>

typedef unsigned short u16;
typedef __bf16 bf16x8 __attribute__((ext_vector_type(8)));
typedef float f32x4 __attribute__((ext_vector_type(4)));
typedef u16 u16x4 __attribute__((ext_vector_type(4)));

#define B_ 2
#define L_ 2048
#define D_ 128
#define KLAY 3
#define NR 16
#define DD (D_ * D_)
#define XTN (L_ * D_)
#define BL (B_ * L_)
#define BLN (BL * NR)
#define NFOLD 6

static __device__ __forceinline__ u16 f2bf(float f) {
    union { float f; unsigned u; } v; v.f = f;
    unsigned r = v.u + 0x7FFFu + ((v.u >> 16) & 1u);
    return (u16)(r >> 16);
}
static __device__ __forceinline__ bf16x8 ld_bf8(const u16* p) {
    return *(const bf16x8*)p;
}

// ---------------- pairw: blocks 0..5 = weight folds; blocks 6..1029 =
// (rt, jq) RBF + rowsum partials (4-group grouped-exp, proven numerics) ----------------
__global__ __launch_bounds__(512) void pairw_kernel(
    const float* coords, const float* gamma_p, const float* centers,
    const float* self_w, const float* msg_w, const float* upd_w,
    const float* self_b, const float* msg_b, const float* upd_b,
    float* rbfp, float* rsp, u16* foldA, u16* foldB, float* c0v, float* cvv) {
    int bid = blockIdx.x;
    int tid = threadIdx.x;
    __shared__ __align__(16) char smem[34816];
    f32x4 z = {0.f, 0.f, 0.f, 0.f};

    if (bid < NFOLD) {
        int w = tid >> 6, lane = tid & 63;
        int rowf = lane & 15, kg = lane >> 4;
        int lay = bid >> 1, mat = bid & 1;
        const float* Wsrc = (mat ? msg_w : self_w) + lay * DD;
        const float* U = upd_w + lay * 2 * DD + mat * DD;
        u16* dst = (mat ? foldB : foldA) + lay * DD;
        u16(*A_l)[68] = (u16(*)[68])smem;
        u16(*BT_l)[68] = (u16(*)[68])(smem + 17408);
        f32x4 acc[8] = {z, z, z, z, z, z, z, z};
        for (int half = 0; half < 2; half++) {
            int m0 = half * 64;
            for (int o = tid; o < 128 * 64; o += 512) {
                int kk = o >> 6, mm = o & 63;
                A_l[kk][mm] = f2bf(Wsrc[kk * D_ + m0 + mm]);
            }
            for (int o = tid; o < 128 * 64; o += 512) {
                int nn = o >> 6, mm = o & 63;
                BT_l[nn][mm] = f2bf(U[(m0 + mm) * D_ + nn]);
            }
            __syncthreads();
#pragma unroll
            for (int rf = 0; rf < 8; rf++)
#pragma unroll
                for (int ks = 0; ks < 2; ks++) {
                    int k0 = ks * 32 + kg * 8;
                    acc[rf] = __builtin_amdgcn_mfma_f32_16x16x32_bf16(
                        ld_bf8(&A_l[rf * 16 + rowf][k0]),
                        ld_bf8(&BT_l[w * 16 + rowf][k0]), acc[rf], 0, 0, 0);
                }
            __syncthreads();
        }
        int n = w * 16 + rowf;
#pragma unroll
        for (int rf = 0; rf < 8; rf++) {
            u16x4 pk;
#pragma unroll
            for (int r = 0; r < 4; r++) pk[r] = f2bf(acc[rf][r]);
            *(u16x4*)&dst[n * D_ + rf * 16 + kg * 4] = pk;
        }
        if (tid < D_) {
            const float* bsrc = (mat ? msg_b : self_b) + lay * D_;
            float s = 0.f;
            for (int m = 0; m < D_; m++) s += bsrc[m] * U[m * D_ + tid];
            if (mat == 0) c0v[lay * D_ + tid] = s + upd_b[lay * D_ + tid];
            else cvv[lay * D_ + tid] = s;
        }
        return;
    }

    // ---- RBF partial block: (rt, jq) ----
    int e6 = bid - NFOLD;
    int rt = e6 >> 2, jq = e6 & 3;
    int gi0 = rt * 16;
    int b = gi0 >> 11;
    int prow = tid >> 5, s5 = tid & 31;
    int gi = gi0 + prow;
    float* cj = (float*)smem;  // 6144 B
    {
        const float4* src = (const float4*)(coords + ((size_t)b * L_ + jq * 512) * 3);
        if (tid < 384) ((float4*)cj)[tid] = src[tid];
    }
    float gamma = gamma_p[0];
    float dl = centers[1] - centers[0];
    float c4[4];
#pragma unroll
    for (int g = 0; g < 4; g++) c4[g] = centers[4 * g];
    float two_gdl = 2.f * gamma * dl;
    float cx = coords[gi * 3 + 0];
    float cy = coords[gi * 3 + 1];
    float cz = coords[gi * 3 + 2];
    __syncthreads();

    float acc[4][4];
#pragma unroll
    for (int g = 0; g < 4; g++)
#pragma unroll
        for (int m = 0; m < 4; m++) acc[g][m] = 0.f;
    float wsum = 0.f;
#pragma unroll 4
    for (int it = 0; it < 16; it++) {
        int jl = s5 + 32 * it;
        float dx = cx - cj[jl * 3 + 0];
        float dy = cy - cj[jl * 3 + 1];
        float dz = cz - cj[jl * 3 + 2];
        float sq = dx * dx + dy * dy + dz * dz;
        float d = sqrtf(sq);
        wsum += __expf(-d);
#pragma unroll
        for (int g = 0; g < 4; g++) {
            float x = d - c4[g];
            float base = __expf(-gamma * x * x);
            float u1 = __expf(fminf(two_gdl * x, 29.f));
            float u2 = u1 * u1;
            acc[g][0] += base;
            acc[g][1] += base * u1;
            acc[g][2] += base * u2;
            acc[g][3] += base * (u2 * u1);
        }
    }
#pragma unroll
    for (int off = 16; off > 0; off >>= 1) {
        wsum += __shfl_xor(wsum, off);
#pragma unroll
        for (int g = 0; g < 4; g++)
#pragma unroll
            for (int m = 0; m < 4; m++) acc[g][m] += __shfl_xor(acc[g][m], off);
    }
    if (s5 == 0) {
        rsp[(size_t)jq * BL + gi] = wsum;
#pragma unroll
        for (int m = 0; m < 4; m++) {
            float Km = __expf(-gamma * (m * dl) * (m * dl)) * (1.0f / L_);
#pragma unroll
            for (int g = 0; g < 4; g++)
                rbfp[(size_t)jq * BLN + (size_t)gi * NR + 4 * g + m] = acc[g][m] * Km;
        }
    }
}

// ---------------- encf: combine partials + encoder MFMA -> h0, h0^T, rowsum ----------------
__global__ __launch_bounds__(256) void encf_kernel(
    const int* Z, const float* atom_emb, const float* rbf_w, const float* rbf_b,
    const float* out_w, const float* out_b, const float* rbfp, const float* rsp,
    u16* h_rm, u16* hT, float* rowsum) {
    int gi0 = blockIdx.x * 16;
    int b = gi0 >> 11;
    int il0 = gi0 & (L_ - 1);
    int tid = threadIdx.x;
    int w = tid >> 6, lane = tid & 63;
    int rowf = lane & 15, kg = lane >> 4;
    __shared__ float rbf_lds[16][NR];
    __shared__ __align__(16) u16 hgeo[16][136];

    {
        int row = tid >> 4, r = tid & 15;
        float s = 0.f;
#pragma unroll
        for (int p = 0; p < 4; p++)
            s += rbfp[(size_t)p * BLN + (size_t)(gi0 + row) * NR + r];
        rbf_lds[row][r] = s;
    }
    if (tid < 16) {
        float s = 0.f;
#pragma unroll
        for (int p = 0; p < 4; p++) s += rsp[(size_t)p * BL + gi0 + tid];
        rowsum[gi0 + tid] = s;
    }
    __syncthreads();
    for (int e = tid; e < 16 * D_; e += 256) {
        int row = e >> 7, d = e & 127;
        float s = rbf_b[d];
#pragma unroll
        for (int r = 0; r < NR; r++) s += rbf_lds[row][r] * rbf_w[r * D_ + d];
        hgeo[row][d] = f2bf(s);
    }
    __syncthreads();

    f32x4 z = {0.f, 0.f, 0.f, 0.f};
    int za = Z[gi0 + rowf];
#pragma unroll
    for (int q = 0; q < 2; q++) {
        int cl = (w * 2 + q) * 16 + rowf;
        f32x4 a1 = z;
#pragma unroll
        for (int ks = 0; ks < 8; ks++) {
            int k0 = ks * 32 + kg * 8;
            bf16x8 av;
            if (k0 < 128) {
                union { bf16x8 v; u16 e[8]; } t;
                const float* ap = atom_emb + (size_t)za * D_ + k0;
#pragma unroll
                for (int e = 0; e < 8; e++) t.e[e] = f2bf(ap[e]);
                av = t.v;
            } else {
                av = ld_bf8(&hgeo[rowf][k0 - 128]);
            }
            union { bf16x8 v; u16 e[8]; } bv;
            const float* bp = out_w + (size_t)k0 * D_ + cl;
#pragma unroll
            for (int e = 0; e < 8; e++) bv.e[e] = f2bf(bp[e * D_]);
            a1 = __builtin_amdgcn_mfma_f32_16x16x32_bf16(av, bv.v, a1, 0, 0, 0);
        }
        float bias = out_b[cl];
        u16x4 pk;
#pragma unroll
        for (int r = 0; r < 4; r++) pk[r] = f2bf(a1[r] + bias);
#pragma unroll
        for (int r = 0; r < 4; r++)
            h_rm[(size_t)(gi0 + kg * 4 + r) * D_ + cl] = pk[r];
        int jj = il0 + kg * 4;
        *(u16x4*)&hT[(size_t)b * XTN + (jj >> 5) * (32 * D_) + cl * 32 + (jj & 31)] = pk;
    }
}

// ---------------- mp: 16 waves; g = W@h (W inline, coords from L1/L2);
// 4-slot LDS reduce; folded epilogue h' = h@A + g@B + c0 + rowsum*cv ----------------
__global__ __launch_bounds__(1024) void mp_kernel(
    const float* coords, const u16* h_in, const u16* hT_in, const float* rowsum,
    const u16* foldA_k, const u16* foldB_k, const float* c0_k, const float* cv_k,
    u16* h_out, u16* hT_out, float* out_f32, int last) {
    int rt = blockIdx.x;
    int gi0 = rt * 16;
    int b = gi0 >> 11;
    int il0 = gi0 & (L_ - 1);
    int tid = threadIdx.x;
    int w = tid >> 6, lane = tid & 63;
    int rowf = lane & 15, kg = lane >> 4;

    __shared__ __align__(16) float red[4][16][128];  // 32 KB
    u16* g_lds = (u16*)&red[0][0][0];                // [16][136] bf16 alias

    const float* cb = coords + (size_t)b * L_ * 3;
    float rx = cb[(il0 + rowf) * 3 + 0];
    float ry = cb[(il0 + rowf) * 3 + 1];
    float rz = cb[(il0 + rowf) * 3 + 2];

    f32x4 z = {0.f, 0.f, 0.f, 0.f};
    f32x4 acc[8] = {z, z, z, z, z, z, z, z};
    const u16* xbase = hT_in + (size_t)b * XTN + (w * 4) * (32 * D_) + rowf * 32 + kg * 8;
#pragma unroll
    for (int s = 0; s < 4; s++) {
        int j0 = w * 128 + s * 32 + kg * 8;
        union { bf16x8 v; __bf16 e[8]; } wf;
#pragma unroll
        for (int e = 0; e < 8; e++) {
            int jl = j0 + e;
            float dx = rx - cb[jl * 3 + 0];
            float dy = ry - cb[jl * 3 + 1];
            float dz = rz - cb[jl * 3 + 2];
            float sq = dx * dx + dy * dy + dz * dz;
            float d = sq > 0.f ? sqrtf(sq) : 0.f;
            wf.e[e] = (__bf16)__expf(-d);
        }
#pragma unroll
        for (int n = 0; n < 8; n++) {
            bf16x8 bb = ld_bf8(xbase + s * (32 * D_) + n * 512);
            acc[n] = __builtin_amdgcn_mfma_f32_16x16x32_bf16(wf.v, bb, acc[n], 0, 0, 0);
        }
    }
    // ---- 16->1 reduce with 4 LDS slots ----
    auto stash = [&](int slot) {
#pragma unroll
        for (int n = 0; n < 8; n++)
#pragma unroll
            for (int r = 0; r < 4; r++) {
                int row = kg * 4 + r, col = n * 16 + rowf;
                red[slot][row][(col + 4 * row) & 127] = acc[n][r];
            }
    };
    auto grab = [&](int slot) {
#pragma unroll
        for (int n = 0; n < 8; n++)
#pragma unroll
            for (int r = 0; r < 4; r++) {
                int row = kg * 4 + r, col = n * 16 + rowf;
                acc[n][r] += red[slot][row][(col + 4 * row) & 127];
            }
    };
    if (w >= 8 && w < 12) stash(w - 8);
    __syncthreads();
    if (w < 4) grab(w);
    __syncthreads();
    if (w >= 12) stash(w - 12);
    __syncthreads();
    if (w >= 4 && w < 8) grab(w - 4);
    __syncthreads();
    if (w >= 4 && w < 8) stash(w - 4);
    __syncthreads();
    if (w < 4) grab(w);
    if (w == 2 || w == 3) stash(w);
    __syncthreads();
    if (w < 2) grab(w + 2);
    if (w == 1) stash(3);
    __syncthreads();
    if (w == 0) {
        grab(3);
#pragma unroll
        for (int n = 0; n < 8; n++)
#pragma unroll
            for (int r = 0; r < 4; r++)
                g_lds[(kg * 4 + r) * 136 + n * 16 + rowf] = f2bf(acc[n][r]);
    }
    __syncthreads();

    // folded epilogue on waves 0-7: h' = h@A + g@B + c0 + rowsum*cv
    if (w < 8) {
        f32x4 acc2 = z;
        int cl = w * 16 + rowf;
#pragma unroll
        for (int ks = 0; ks < 4; ks++) {
            int k0 = ks * 32 + kg * 8;
            bf16x8 ah = ld_bf8(h_in + (size_t)(gi0 + rowf) * D_ + k0);
            acc2 = __builtin_amdgcn_mfma_f32_16x16x32_bf16(
                ah, ld_bf8(foldA_k + cl * D_ + k0), acc2, 0, 0, 0);
            bf16x8 ag = ld_bf8(g_lds + rowf * 136 + k0);
            acc2 = __builtin_amdgcn_mfma_f32_16x16x32_bf16(
                ag, ld_bf8(foldB_k + cl * D_ + k0), acc2, 0, 0, 0);
        }
        float c0 = c0_k[cl], cv = cv_k[cl];
        if (last) {
#pragma unroll
            for (int r = 0; r < 4; r++) {
                int row = kg * 4 + r;
                out_f32[(size_t)(gi0 + row) * D_ + cl] =
                    acc2[r] + c0 + rowsum[gi0 + row] * cv;
            }
        } else {
#pragma unroll
            for (int r = 0; r < 4; r++) {
                int row = kg * 4 + r;
                float val = acc2[r] + c0 + rowsum[gi0 + row] * cv;
                u16 hv = f2bf(val);
                h_out[(size_t)(gi0 + row) * D_ + cl] = hv;
                int jj = il0 + row;
                hT_out[(size_t)b * XTN + (jj >> 5) * (32 * D_) + cl * 32 + (jj & 31)] = hv;
            }
        }
    }
}

extern "C" void kernel_launch(void* const* d_in, const int* in_sizes, int n_in,
                              void* d_out, int out_size, void* d_ws, size_t ws_size,
                              hipStream_t stream) {
    const float* coords = (const float*)d_in[0];
    const int* Z = (const int*)d_in[1];
    const float* atom_emb = (const float*)d_in[2];
    const float* gamma = (const float*)d_in[3];
    const float* centers = (const float*)d_in[4];
    const float* rbf_w = (const float*)d_in[5];
    const float* rbf_b = (const float*)d_in[6];
    const float* out_w = (const float*)d_in[7];
    const float* out_b = (const float*)d_in[8];
    const float* self_w = (const float*)d_in[9];
    const float* self_b = (const float*)d_in[10];
    const float* msg_w = (const float*)d_in[11];
    const float* msg_b = (const float*)d_in[12];
    const float* upd_w = (const float*)d_in[13];
    const float* upd_b = (const float*)d_in[14];
    float* out = (float*)d_out;

    char* ws = (char*)d_ws;
    u16* h_a = (u16*)(ws + 0);               // 1,048,576
    u16* h_b = (u16*)(ws + 1048576);         // 1,048,576
    u16* hT_a = (u16*)(ws + 2097152);        // 1,048,576
    u16* hT_b = (u16*)(ws + 3145728);        // 1,048,576
    float* rowsum = (float*)(ws + 4194304);  // 16,384
    u16* foldA = (u16*)(ws + 4210688);       // 98,304
    u16* foldB = (u16*)(ws + 4308992);       // 98,304
    float* c0v = (float*)(ws + 4407296);     // 1,536
    float* cvv = (float*)(ws + 4408832);     // 1,536
    float* rbfp = (float*)(ws + 4410368);    // 1,048,576
    float* rsp = (float*)(ws + 5458944);     // 65,536

    pairw_kernel<<<NFOLD + 1024, 512, 0, stream>>>(
        coords, gamma, centers, self_w, msg_w, upd_w, self_b, msg_b, upd_b,
        rbfp, rsp, foldA, foldB, c0v, cvv);
    encf_kernel<<<256, 256, 0, stream>>>(
        Z, atom_emb, rbf_w, rbf_b, out_w, out_b, rbfp, rsp, h_a, hT_a, rowsum);
    // layer 0: a -> b
    mp_kernel<<<256, 1024, 0, stream>>>(
        coords, h_a, hT_a, rowsum, foldA + 0 * DD, foldB + 0 * DD,
        c0v + 0 * D_, cvv + 0 * D_, h_b, hT_b, out, 0);
    // layer 1: b -> a
    mp_kernel<<<256, 1024, 0, stream>>>(
        coords, h_b, hT_b, rowsum, foldA + 1 * DD, foldB + 1 * DD,
        c0v + 1 * D_, cvv + 1 * D_, h_a, hT_a, out, 0);
    // layer 2 (last): a -> out
    mp_kernel<<<256, 1024, 0, stream>>>(
        coords, h_a, hT_a, rowsum, foldA + 2 * DD, foldB + 2 * DD,
        c0v + 2 * D_, cvv + 2 * D_, h_b, hT_b, out, 1);
}

// Round 19
// 98.221 us; speedup vs baseline: 1.0425x; 1.0425x over previous
//
#include <hip/hip_runtime.h>
#include <hip/hip_bf16.h>

typedef unsigned short u16;
typedef __bf16 bf16x8 __attribute__((ext_vector_type(8)));
typedef float f32x4 __attribute__((ext_vector_type(4)));
typedef u16 u16x4 __attribute__((ext_vector_type(4)));

#define B_ 2
#define L_ 2048
#define D_ 128
#define KLAY 3
#define NR 16
#define DD (D_ * D_)
#define XTN (L_ * D_)
#define BL (B_ * L_)
#define BLN (BL * NR)
#define NFOLD 6

static __device__ __forceinline__ u16 f2bf(float f) {
    union { float f; unsigned u; } v; v.f = f;
    unsigned r = v.u + 0x7FFFu + ((v.u >> 16) & 1u);
    return (u16)(r >> 16);
}
static __device__ __forceinline__ bf16x8 ld_bf8(const u16* p) {
    return *(const bf16x8*)p;
}

// ---------------- pairw: blocks 0..5 = weight folds; blocks 6..1029 =
// (rt, jq) RBF + rowsum partials ----------------
__global__ __launch_bounds__(512) void pairw_kernel(
    const float* coords, const float* gamma_p, const float* centers,
    const float* self_w, const float* msg_w, const float* upd_w,
    const float* self_b, const float* msg_b, const float* upd_b,
    float* rbfp, float* rsp, u16* foldA, u16* foldB, float* c0v, float* cvv) {
    int bid = blockIdx.x;
    int tid = threadIdx.x;
    __shared__ __align__(16) char smem[34816];
    f32x4 z = {0.f, 0.f, 0.f, 0.f};

    if (bid < NFOLD) {
        // ---- fold: F = Wsrc @ U (bf16 [n][k]) via LDS-staged MFMA ----
        int w = tid >> 6, lane = tid & 63;
        int rowf = lane & 15, kg = lane >> 4;
        int lay = bid >> 1, mat = bid & 1;
        const float* Wsrc = (mat ? msg_w : self_w) + lay * DD;  // [k][m]
        const float* U = upd_w + lay * 2 * DD + mat * DD;       // [m][n]
        u16* dst = (mat ? foldB : foldA) + lay * DD;            // [n][k]
        u16(*A_l)[68] = (u16(*)[68])smem;             // [128][68] rows=k
        u16(*BT_l)[68] = (u16(*)[68])(smem + 17408);  // [128][68] rows=n
        f32x4 acc[8] = {z, z, z, z, z, z, z, z};
        for (int half = 0; half < 2; half++) {
            int m0 = half * 64;
            for (int o = tid; o < 128 * 64; o += 512) {
                int kk = o >> 6, mm = o & 63;
                A_l[kk][mm] = f2bf(Wsrc[kk * D_ + m0 + mm]);
            }
            for (int o = tid; o < 128 * 64; o += 512) {
                int nn = o >> 6, mm = o & 63;
                BT_l[nn][mm] = f2bf(U[(m0 + mm) * D_ + nn]);
            }
            __syncthreads();
#pragma unroll
            for (int rf = 0; rf < 8; rf++)
#pragma unroll
                for (int ks = 0; ks < 2; ks++) {
                    int k0 = ks * 32 + kg * 8;
                    acc[rf] = __builtin_amdgcn_mfma_f32_16x16x32_bf16(
                        ld_bf8(&A_l[rf * 16 + rowf][k0]),
                        ld_bf8(&BT_l[w * 16 + rowf][k0]), acc[rf], 0, 0, 0);
                }
            __syncthreads();
        }
        int n = w * 16 + rowf;
#pragma unroll
        for (int rf = 0; rf < 8; rf++) {
            u16x4 pk;
#pragma unroll
            for (int r = 0; r < 4; r++) pk[r] = f2bf(acc[rf][r]);
            *(u16x4*)&dst[n * D_ + rf * 16 + kg * 4] = pk;
        }
        if (tid < D_) {
            const float* bsrc = (mat ? msg_b : self_b) + lay * D_;
            float s = 0.f;
            for (int m = 0; m < D_; m++) s += bsrc[m] * U[m * D_ + tid];
            if (mat == 0) c0v[lay * D_ + tid] = s + upd_b[lay * D_ + tid];
            else cvv[lay * D_ + tid] = s;
        }
        return;
    }

    // ---- RBF partial block: (rt, jq) ----
    int e6 = bid - NFOLD;
    int rt = e6 >> 2, jq = e6 & 3;
    int gi0 = rt * 16;
    int b = gi0 >> 11;
    int prow = tid >> 5, s5 = tid & 31;
    int gi = gi0 + prow;
    float* cj = (float*)smem;  // 6144 B
    {
        const float4* src = (const float4*)(coords + ((size_t)b * L_ + jq * 512) * 3);
        if (tid < 384) ((float4*)cj)[tid] = src[tid];
    }
    float gamma = gamma_p[0];
    float dl = centers[1] - centers[0];
    float c4[4];
#pragma unroll
    for (int g = 0; g < 4; g++) c4[g] = centers[4 * g];
    float two_gdl = 2.f * gamma * dl;
    float cx = coords[gi * 3 + 0];
    float cy = coords[gi * 3 + 1];
    float cz = coords[gi * 3 + 2];
    __syncthreads();

    float acc[4][4];
#pragma unroll
    for (int g = 0; g < 4; g++)
#pragma unroll
        for (int m = 0; m < 4; m++) acc[g][m] = 0.f;
    float wsum = 0.f;
#pragma unroll 4
    for (int it = 0; it < 16; it++) {
        int jl = s5 + 32 * it;
        float dx = cx - cj[jl * 3 + 0];
        float dy = cy - cj[jl * 3 + 1];
        float dz = cz - cj[jl * 3 + 2];
        float sq = dx * dx + dy * dy + dz * dz;
        float d = sqrtf(sq);
        wsum += __expf(-d);
#pragma unroll
        for (int g = 0; g < 4; g++) {
            float x = d - c4[g];
            float base = __expf(-gamma * x * x);
            float u1 = __expf(fminf(two_gdl * x, 29.f));
            float u2 = u1 * u1;
            acc[g][0] += base;
            acc[g][1] += base * u1;
            acc[g][2] += base * u2;
            acc[g][3] += base * (u2 * u1);
        }
    }
#pragma unroll
    for (int off = 16; off > 0; off >>= 1) {
        wsum += __shfl_xor(wsum, off);
#pragma unroll
        for (int g = 0; g < 4; g++)
#pragma unroll
            for (int m = 0; m < 4; m++) acc[g][m] += __shfl_xor(acc[g][m], off);
    }
    if (s5 == 0) {
        rsp[(size_t)jq * BL + gi] = wsum;
#pragma unroll
        for (int m = 0; m < 4; m++) {
            float Km = __expf(-gamma * (m * dl) * (m * dl)) * (1.0f / L_);
#pragma unroll
            for (int g = 0; g < 4; g++)
                rbfp[(size_t)jq * BLN + (size_t)gi * NR + 4 * g + m] = acc[g][m] * Km;
        }
    }
}

// ---------------- encf: combine partials + encoder MFMA -> h0, h0^T, rowsum ----------------
__global__ __launch_bounds__(256) void encf_kernel(
    const int* Z, const float* atom_emb, const float* rbf_w, const float* rbf_b,
    const float* out_w, const float* out_b, const float* rbfp, const float* rsp,
    u16* h_rm, u16* hT, float* rowsum) {
    int gi0 = blockIdx.x * 16;
    int b = gi0 >> 11;
    int il0 = gi0 & (L_ - 1);
    int tid = threadIdx.x;
    int w = tid >> 6, lane = tid & 63;
    int rowf = lane & 15, kg = lane >> 4;
    __shared__ float rbf_lds[16][NR];
    __shared__ __align__(16) u16 hgeo[16][136];

    {
        int row = tid >> 4, r = tid & 15;
        float s = 0.f;
#pragma unroll
        for (int p = 0; p < 4; p++)
            s += rbfp[(size_t)p * BLN + (size_t)(gi0 + row) * NR + r];
        rbf_lds[row][r] = s;
    }
    if (tid < 16) {
        float s = 0.f;
#pragma unroll
        for (int p = 0; p < 4; p++) s += rsp[(size_t)p * BL + gi0 + tid];
        rowsum[gi0 + tid] = s;
    }
    __syncthreads();
    for (int e = tid; e < 16 * D_; e += 256) {
        int row = e >> 7, d = e & 127;
        float s = rbf_b[d];
#pragma unroll
        for (int r = 0; r < NR; r++) s += rbf_lds[row][r] * rbf_w[r * D_ + d];
        hgeo[row][d] = f2bf(s);
    }
    __syncthreads();

    // encoder MFMA: 4 waves x 2 col-blocks
    f32x4 z = {0.f, 0.f, 0.f, 0.f};
    int za = Z[gi0 + rowf];
#pragma unroll
    for (int q = 0; q < 2; q++) {
        int cl = (w * 2 + q) * 16 + rowf;
        f32x4 a1 = z;
#pragma unroll
        for (int ks = 0; ks < 8; ks++) {
            int k0 = ks * 32 + kg * 8;
            bf16x8 av;
            if (k0 < 128) {
                union { bf16x8 v; u16 e[8]; } t;
                const float* ap = atom_emb + (size_t)za * D_ + k0;
#pragma unroll
                for (int e = 0; e < 8; e++) t.e[e] = f2bf(ap[e]);
                av = t.v;
            } else {
                av = ld_bf8(&hgeo[rowf][k0 - 128]);
            }
            union { bf16x8 v; u16 e[8]; } bv;
            const float* bp = out_w + (size_t)k0 * D_ + cl;
#pragma unroll
            for (int e = 0; e < 8; e++) bv.e[e] = f2bf(bp[e * D_]);
            a1 = __builtin_amdgcn_mfma_f32_16x16x32_bf16(av, bv.v, a1, 0, 0, 0);
        }
        float bias = out_b[cl];
        u16x4 pk;
#pragma unroll
        for (int r = 0; r < 4; r++) pk[r] = f2bf(a1[r] + bias);
#pragma unroll
        for (int r = 0; r < 4; r++)
            h_rm[(size_t)(gi0 + kg * 4 + r) * D_ + cl] = pk[r];
        int jj = il0 + kg * 4;
        *(u16x4*)&hT[(size_t)b * XTN + (jj >> 5) * (32 * D_) + cl * 32 + (jj & 31)] = pk;
    }
}

// ---------------- mp: 16 waves; g = W@h (W inline, j 128/wave);
// 4-slot LDS reduce; h' = h@A + g@B + c0 + rowsum*cv ----------------
__global__ __launch_bounds__(1024) void mp_kernel(
    const float* coords, const u16* h_in, const u16* hT_in, const float* rowsum,
    const u16* foldA_k, const u16* foldB_k, const float* c0_k, const float* cv_k,
    u16* h_out, u16* hT_out, float* out_f32, int last) {
    int rt = blockIdx.x;
    int gi0 = rt * 16;
    int b = gi0 >> 11;
    int il0 = gi0 & (L_ - 1);
    int tid = threadIdx.x;
    int w = tid >> 6, lane = tid & 63;
    int rowf = lane & 15, kg = lane >> 4;

    __shared__ __align__(16) float cj[L_ * 3];       // 24 KB
    __shared__ __align__(16) float red[4][16][128];  // 32 KB
    u16* g_lds = (u16*)&red[0][0][0];                // [16][136] bf16 alias

    for (int i = tid; i < 1536; i += 1024)
        ((float4*)cj)[i] = ((const float4*)(coords + (size_t)b * L_ * 3))[i];
    __syncthreads();

    float rx = cj[(il0 + rowf) * 3 + 0];
    float ry = cj[(il0 + rowf) * 3 + 1];
    float rz = cj[(il0 + rowf) * 3 + 2];

    f32x4 z = {0.f, 0.f, 0.f, 0.f};
    f32x4 acc[8] = {z, z, z, z, z, z, z, z};
    // wave w owns j in [w*128, w*128+128): 4 slices of 32
    const u16* xbase = hT_in + (size_t)b * XTN + (w * 4) * (32 * D_) + rowf * 32 + kg * 8;
#pragma unroll
    for (int s = 0; s < 4; s++) {
        int j0 = w * 128 + s * 32 + kg * 8;
        union { bf16x8 v; __bf16 e[8]; } wf;
#pragma unroll
        for (int e = 0; e < 8; e++) {
            int jl = j0 + e;
            float dx = rx - cj[jl * 3 + 0];
            float dy = ry - cj[jl * 3 + 1];
            float dz = rz - cj[jl * 3 + 2];
            float sq = dx * dx + dy * dy + dz * dz;
            float d = sq > 0.f ? sqrtf(sq) : 0.f;
            wf.e[e] = (__bf16)__expf(-d);
        }
#pragma unroll
        for (int n = 0; n < 8; n++) {
            bf16x8 bb = ld_bf8(xbase + s * (32 * D_) + n * 512);
            acc[n] = __builtin_amdgcn_mfma_f32_16x16x32_bf16(wf.v, bb, acc[n], 0, 0, 0);
        }
    }
    // ---- 16->1 reduce with 4 LDS slots ----
    auto stash = [&](int slot) {
#pragma unroll
        for (int n = 0; n < 8; n++)
#pragma unroll
            for (int r = 0; r < 4; r++) {
                int row = kg * 4 + r, col = n * 16 + rowf;
                red[slot][row][(col + 4 * row) & 127] = acc[n][r];
            }
    };
    auto grab = [&](int slot) {
#pragma unroll
        for (int n = 0; n < 8; n++)
#pragma unroll
            for (int r = 0; r < 4; r++) {
                int row = kg * 4 + r, col = n * 16 + rowf;
                acc[n][r] += red[slot][row][(col + 4 * row) & 127];
            }
    };
    if (w >= 8 && w < 12) stash(w - 8);
    __syncthreads();
    if (w < 4) grab(w);
    __syncthreads();
    if (w >= 12) stash(w - 12);
    __syncthreads();
    if (w >= 4 && w < 8) grab(w - 4);
    __syncthreads();
    if (w >= 4 && w < 8) stash(w - 4);
    __syncthreads();
    if (w < 4) grab(w);
    if (w == 2 || w == 3) stash(w);
    __syncthreads();
    if (w < 2) grab(w + 2);
    if (w == 1) stash(3);
    __syncthreads();
    if (w == 0) {
        grab(3);
#pragma unroll
        for (int n = 0; n < 8; n++)
#pragma unroll
            for (int r = 0; r < 4; r++)
                g_lds[(kg * 4 + r) * 136 + n * 16 + rowf] = f2bf(acc[n][r]);
    }
    __syncthreads();

    // folded epilogue on waves 0-7: h' = h@A + g@B + c0 + rowsum*cv
    if (w < 8) {
        f32x4 acc2 = z;
        int cl = w * 16 + rowf;
#pragma unroll
        for (int ks = 0; ks < 4; ks++) {
            int k0 = ks * 32 + kg * 8;
            bf16x8 ah = ld_bf8(h_in + (size_t)(gi0 + rowf) * D_ + k0);
            acc2 = __builtin_amdgcn_mfma_f32_16x16x32_bf16(
                ah, ld_bf8(foldA_k + cl * D_ + k0), acc2, 0, 0, 0);
            bf16x8 ag = ld_bf8(g_lds + rowf * 136 + k0);
            acc2 = __builtin_amdgcn_mfma_f32_16x16x32_bf16(
                ag, ld_bf8(foldB_k + cl * D_ + k0), acc2, 0, 0, 0);
        }
        float c0 = c0_k[cl], cv = cv_k[cl];
        if (last) {
#pragma unroll
            for (int r = 0; r < 4; r++) {
                int row = kg * 4 + r;
                out_f32[(size_t)(gi0 + row) * D_ + cl] =
                    acc2[r] + c0 + rowsum[gi0 + row] * cv;
            }
        } else {
#pragma unroll
            for (int r = 0; r < 4; r++) {
                int row = kg * 4 + r;
                float val = acc2[r] + c0 + rowsum[gi0 + row] * cv;
                u16 hv = f2bf(val);
                h_out[(size_t)(gi0 + row) * D_ + cl] = hv;
                int jj = il0 + row;
                hT_out[(size_t)b * XTN + (jj >> 5) * (32 * D_) + cl * 32 + (jj & 31)] = hv;
            }
        }
    }
}

extern "C" void kernel_launch(void* const* d_in, const int* in_sizes, int n_in,
                              void* d_out, int out_size, void* d_ws, size_t ws_size,
                              hipStream_t stream) {
    const float* coords = (const float*)d_in[0];
    const int* Z = (const int*)d_in[1];
    const float* atom_emb = (const float*)d_in[2];
    const float* gamma = (const float*)d_in[3];
    const float* centers = (const float*)d_in[4];
    const float* rbf_w = (const float*)d_in[5];
    const float* rbf_b = (const float*)d_in[6];
    const float* out_w = (const float*)d_in[7];
    const float* out_b = (const float*)d_in[8];
    const float* self_w = (const float*)d_in[9];
    const float* self_b = (const float*)d_in[10];
    const float* msg_w = (const float*)d_in[11];
    const float* msg_b = (const float*)d_in[12];
    const float* upd_w = (const float*)d_in[13];
    const float* upd_b = (const float*)d_in[14];
    float* out = (float*)d_out;

    char* ws = (char*)d_ws;
    u16* h_a = (u16*)(ws + 0);               // 1,048,576
    u16* h_b = (u16*)(ws + 1048576);         // 1,048,576
    u16* hT_a = (u16*)(ws + 2097152);        // 1,048,576
    u16* hT_b = (u16*)(ws + 3145728);        // 1,048,576
    float* rowsum = (float*)(ws + 4194304);  // 16,384
    u16* foldA = (u16*)(ws + 4210688);       // 98,304
    u16* foldB = (u16*)(ws + 4308992);       // 98,304
    float* c0v = (float*)(ws + 4407296);     // 1,536
    float* cvv = (float*)(ws + 4408832);     // 1,536
    float* rbfp = (float*)(ws + 4410368);    // 1,048,576
    float* rsp = (float*)(ws + 5458944);     // 65,536

    pairw_kernel<<<NFOLD + 1024, 512, 0, stream>>>(
        coords, gamma, centers, self_w, msg_w, upd_w, self_b, msg_b, upd_b,
        rbfp, rsp, foldA, foldB, c0v, cvv);
    encf_kernel<<<256, 256, 0, stream>>>(
        Z, atom_emb, rbf_w, rbf_b, out_w, out_b, rbfp, rsp, h_a, hT_a, rowsum);
    // layer 0: a -> b
    mp_kernel<<<256, 1024, 0, stream>>>(
        coords, h_a, hT_a, rowsum, foldA + 0 * DD, foldB + 0 * DD,
        c0v + 0 * D_, cvv + 0 * D_, h_b, hT_b, out, 0);
    // layer 1: b -> a
    mp_kernel<<<256, 1024, 0, stream>>>(
        coords, h_b, hT_b, rowsum, foldA + 1 * DD, foldB + 1 * DD,
        c0v + 1 * D_, cvv + 1 * D_, h_a, hT_a, out, 0);
    // layer 2 (last): a -> out
    mp_kernel<<<256, 1024, 0, stream>>>(
        coords, h_a, hT_a, rowsum, foldA + 2 * DD, foldB + 2 * DD,
        c0v + 2 * D_, cvv + 2 * D_, h_b, hT_b, out, 1);
}